// Round 1
// baseline (1997.862 us; speedup 1.0000x reference)
//
#include <hip/hip_runtime.h>
#include <math.h>

#define B_ 256
#define L_ 256
#define V_ 2048
#define DIN_ 128
#define H_ 256
#define NODES_ 511

__device__ __forceinline__ float sigm(float x) { return 1.f / (1.f + __expf(-x)); }
__device__ __forceinline__ float tanh_f(float x) {
    float xc = fminf(fmaxf(x, -15.f), 15.f);
    float e = __expf(2.f * xc);
    return (e - 1.f) / (e + 1.f);
}

// Build fused weight matrix W_all (640 x 1280), column layout col = g*256 + t
// rows: [0,128) = x part, [128,384) = h1 part, [384,640) = h2 part
// gates g: 0=i, 1=o, 2=u, 3=f0, 4=f1
__global__ void build_wall(float* __restrict__ Wall,
    const float* __restrict__ Wioux, const float* __restrict__ Wfx,
    const float* __restrict__ Wiouh1, const float* __restrict__ Wfh11, const float* __restrict__ Wfh21,
    const float* __restrict__ Wiouh2, const float* __restrict__ Wfh12, const float* __restrict__ Wfh22)
{
    int e = blockIdx.x * 256 + threadIdx.x;          // < 640*1280 = 819200
    int k = e / 1280; int col = e - k * 1280;
    int g = col >> 8; int t = col & 255;
    float v;
    if (k < 128) {
        v = (g < 3) ? Wioux[k * 768 + col] : Wfx[k * 256 + t];
    } else if (k < 384) {
        int kp = k - 128;
        v = (g < 3) ? Wiouh1[kp * 768 + col] : ((g == 3) ? Wfh11[kp * 256 + t] : Wfh21[kp * 256 + t]);
    } else {
        int kp = k - 384;
        v = (g < 3) ? Wiouh2[kp * 768 + col] : ((g == 3) ? Wfh12[kp * 256 + t] : Wfh22[kp * 256 + t]);
    }
    Wall[e] = v;
}

__global__ void build_bias(float* __restrict__ bias,
    const float* __restrict__ bioux, const float* __restrict__ biouh1, const float* __restrict__ biouh2,
    const float* __restrict__ bfx, const float* __restrict__ bfh11, const float* __restrict__ bfh12,
    const float* __restrict__ bfh21, const float* __restrict__ bfh22)
{
    int e = blockIdx.x * 256 + threadIdx.x;
    if (e >= 1280) return;
    int g = e >> 8, t = e & 255;
    float v;
    if (g < 3)       v = bioux[e] + biouh1[e] + biouh2[e];
    else if (g == 3) v = bfx[t] + bfh11[t] + bfh12[t];
    else             v = bfx[t] + bfh21[t] + bfh22[t];
    bias[e] = v;
}

// One tree level. Block: 256 threads = (ry 16) x (tx 16).
// Tile: BM = 16*RPT rows x 32 features (x G gates of those features).
// A row r = b*n + j: [emb[ids[b][off+j]] (128) | h_prev[b][2j] (256) | h_prev[b][2j+1] (256)]
// L0: K=128 (x only), G=3 (i,o,u only), c = i*u.
template<int RPT, bool L0>
__global__ __launch_bounds__(256) void cell_kernel(
    const float* __restrict__ Wall, const float* __restrict__ bias,
    const int* __restrict__ ids, const float* __restrict__ emb,
    const float* __restrict__ h_prev, const float* __restrict__ c_prev,
    float* __restrict__ h_out, float* __restrict__ c_out,
    int n, int ln, int off)
{
    constexpr int BM = 16 * RPT;
    constexpr int G = L0 ? 3 : 5;
    constexpr int KTOT = L0 ? 128 : 640;
    constexpr int KT = 16;
    constexpr int BN = 32 * G;
    __shared__ float As[KT][BM + 4];   // transposed: As[k][row]; row stride (BM+4)*4B is mult of 16
    __shared__ float Bs[KT][BN];       // Bs[k][g*32 + f]

    const int tid = threadIdx.x;
    const int ry = tid >> 4;
    const int tx = tid & 15;
    const int rowBlock = blockIdx.x * BM;
    const int f0 = blockIdx.y * 32;

    float acc[RPT][2][G];
    #pragma unroll
    for (int a = 0; a < RPT; a++)
        #pragma unroll
        for (int b2 = 0; b2 < 2; b2++)
            #pragma unroll
            for (int g = 0; g < G; g++) acc[a][b2][g] = 0.f;

    for (int k0 = 0; k0 < KTOT; k0 += KT) {
        // ---- stage A tile (BM x 16), float4-per-thread along k, transposed store
        for (int idx = tid; idx < BM * 4; idx += 256) {
            int row = idx >> 2; int kk = (idx & 3) << 2;
            int r = rowBlock + row;
            int b = r >> ln; int j = r & (n - 1);
            int k = k0 + kk;
            float4 v = make_float4(0.f, 0.f, 0.f, 0.f);
            if (L0 || k < DIN_) {
                int id = ids[b * NODES_ + off + j];
                if (id != 0) v = *(const float4*)(emb + (size_t)id * DIN_ + k);
            } else {
                int d = (k >= DIN_ + H_) ? 1 : 0;
                int kp = k - DIN_ - d * H_;
                v = *(const float4*)(h_prev + ((size_t)((b * n + j) * 2 + d)) * H_ + kp);
            }
            As[kk + 0][row] = v.x; As[kk + 1][row] = v.y;
            As[kk + 2][row] = v.z; As[kk + 3][row] = v.w;
        }
        // ---- stage B tile (16 x 32G)
        for (int idx = tid; idx < KT * G * 8; idx += 256) {
            int kr = idx / (G * 8); int rem = idx - kr * (G * 8); int g = rem >> 3; int q = rem & 7;
            float4 w = *(const float4*)(Wall + (size_t)(k0 + kr) * 1280 + g * 256 + f0 + q * 4);
            *(float4*)&Bs[kr][g * 32 + q * 4] = w;
        }
        __syncthreads();
        #pragma unroll 4
        for (int k = 0; k < KT; ++k) {
            float a[RPT];
            if constexpr (RPT == 8) {
                float4 a0 = *(const float4*)&As[k][ry * 8];
                float4 a1 = *(const float4*)&As[k][ry * 8 + 4];
                a[0] = a0.x; a[1] = a0.y; a[2] = a0.z; a[3] = a0.w;
                a[4] = a1.x; a[5] = a1.y; a[6] = a1.z; a[7] = a1.w;
            } else if constexpr (RPT == 2) {
                float2 a0 = *(const float2*)&As[k][ry * 2];
                a[0] = a0.x; a[1] = a0.y;
            } else {
                a[0] = As[k][ry];
            }
            #pragma unroll
            for (int g = 0; g < G; ++g) {
                float2 w = *(const float2*)&Bs[k][g * 32 + tx * 2];
                #pragma unroll
                for (int rr = 0; rr < RPT; ++rr) {
                    acc[rr][0][g] = fmaf(a[rr], w.x, acc[rr][0][g]);
                    acc[rr][1][g] = fmaf(a[rr], w.y, acc[rr][1][g]);
                }
            }
        }
        __syncthreads();
    }
    // ---- fused epilogue: gates -> (h, c)
    #pragma unroll
    for (int rr = 0; rr < RPT; ++rr) {
        int r = rowBlock + ry * RPT + rr;
        int b = r >> ln; int j = r & (n - 1);
        #pragma unroll
        for (int fe = 0; fe < 2; ++fe) {
            int t = f0 + tx * 2 + fe;
            float vi = sigm(acc[rr][fe][0] + bias[t]);
            float vo = sigm(acc[rr][fe][1] + bias[256 + t]);
            float vu = tanh_f(acc[rr][fe][2] + bias[512 + t]);
            float c;
            if constexpr (L0) {
                c = vi * vu;
            } else {
                float vf0 = sigm(acc[rr][fe][3] + bias[768 + t]);
                float vf1 = sigm(acc[rr][fe][4] + bias[1024 + t]);
                size_t cb = ((size_t)((b * n + j) * 2)) * H_ + t;
                c = vi * vu + vf0 * c_prev[cb] + vf1 * c_prev[cb + H_];
            }
            float h = vo * tanh_f(c);
            size_t ob = (size_t)r * H_ + t;
            h_out[ob] = h;
            c_out[ob] = c;
        }
    }
}

// Final head: pred[b] = relu(h_root[b] @ Wl1 + bl1) @ Wl2 + bl2
__global__ void head_kernel(const float* __restrict__ hroot,
    const float* __restrict__ Wl1, const float* __restrict__ bl1,
    const float* __restrict__ Wl2, const float* __restrict__ bl2,
    float* __restrict__ out)
{
    __shared__ float hrow[H_];
    __shared__ float red[256];
    int b = blockIdx.x; int tid = threadIdx.x;
    hrow[tid] = hroot[(size_t)b * H_ + tid];
    __syncthreads();
    float v = 0.f;
    if (tid < 100) {
        float s = bl1[tid];
        for (int k = 0; k < H_; k++) s = fmaf(hrow[k], Wl1[k * 100 + tid], s);
        v = fmaxf(s, 0.f) * Wl2[tid];
    }
    red[tid] = v;
    __syncthreads();
    for (int s = 128; s > 0; s >>= 1) { if (tid < s) red[tid] += red[tid + s]; __syncthreads(); }
    if (tid == 0) out[b] = red[0] + bl2[0];
}

extern "C" void kernel_launch(void* const* d_in, const int* in_sizes, int n_in,
                              void* d_out, int out_size, void* d_ws, size_t ws_size,
                              hipStream_t stream) {
    const int*   ids    = (const int*)d_in[0];
    const float* emb    = (const float*)d_in[1];
    const float* Wioux  = (const float*)d_in[2];
    const float* bioux  = (const float*)d_in[3];
    const float* Wiouh1 = (const float*)d_in[4];
    const float* biouh1 = (const float*)d_in[5];
    const float* Wiouh2 = (const float*)d_in[6];
    const float* biouh2 = (const float*)d_in[7];
    const float* Wfx    = (const float*)d_in[8];
    const float* bfx    = (const float*)d_in[9];
    const float* Wfh11  = (const float*)d_in[10];
    const float* bfh11  = (const float*)d_in[11];
    const float* Wfh12  = (const float*)d_in[12];
    const float* bfh12  = (const float*)d_in[13];
    const float* Wfh21  = (const float*)d_in[14];
    const float* bfh21  = (const float*)d_in[15];
    const float* Wfh22  = (const float*)d_in[16];
    const float* bfh22  = (const float*)d_in[17];
    const float* Wl1    = (const float*)d_in[18];
    const float* bl1    = (const float*)d_in[19];
    const float* Wl2    = (const float*)d_in[20];
    const float* bl2    = (const float*)d_in[21];
    float* out = (float*)d_out;

    // workspace layout (floats): W_all 819200 | bias 1280 | hA 16.7M | cA 16.7M | hB 8.4M | cB 8.4M
    // total = 204.6 MB
    float* ws   = (float*)d_ws;
    float* Wall = ws;
    float* bias = Wall + 640 * 1280;
    float* hA   = bias + 1280;
    float* cA   = hA + (size_t)B_ * L_ * H_;
    float* hB   = cA + (size_t)B_ * L_ * H_;
    float* cB   = hB + (size_t)B_ * (L_ / 2) * H_;

    build_wall<<<dim3(3200), 256, 0, stream>>>(Wall, Wioux, Wfx, Wiouh1, Wfh11, Wfh21, Wiouh2, Wfh12, Wfh22);
    build_bias<<<dim3(5), 256, 0, stream>>>(bias, bioux, biouh1, biouh2, bfx, bfh11, bfh12, bfh21, bfh22);

    // level 0: n=256, K=128, gates iou only
    cell_kernel<8, true><<<dim3(512, 8), 256, 0, stream>>>(Wall, bias, ids, emb, hA, cA, hA, cA, 256, 8, 0);

    float *hp = hA, *cp = cA, *hn = hB, *cn = cB;
    int off = 256, n = 128, ln = 7;
    for (int lvl = 1; lvl < 9; ++lvl) {
        int M = B_ * n;
        if (M >= 8192)
            cell_kernel<8, false><<<dim3(M / 128, 8), 256, 0, stream>>>(Wall, bias, ids, emb, hp, cp, hn, cn, n, ln, off);
        else if (M >= 512)
            cell_kernel<2, false><<<dim3(M / 32, 8), 256, 0, stream>>>(Wall, bias, ids, emb, hp, cp, hn, cn, n, ln, off);
        else
            cell_kernel<1, false><<<dim3(M / 16, 8), 256, 0, stream>>>(Wall, bias, ids, emb, hp, cp, hn, cn, n, ln, off);
        off += n; n >>= 1; ln -= 1;
        float* t1 = hp; hp = hn; hn = t1;
        float* t2 = cp; cp = cn; cn = t2;
    }

    head_kernel<<<dim3(256), 256, 0, stream>>>(hp, Wl1, bl1, Wl2, bl2, out);
}

// Round 2
// 368.154 us; speedup vs baseline: 5.4267x; 5.4267x over previous
//
#include <hip/hip_runtime.h>
#include <math.h>

#define B_ 256
#define L_ 256
#define V_ 2048
#define DIN_ 128
#define H_ 256
#define NODES_ 511

typedef _Float16 half8 __attribute__((ext_vector_type(8)));
typedef float f32x4 __attribute__((ext_vector_type(4)));

__device__ __forceinline__ float sigm(float x) { return 1.f / (1.f + __expf(-x)); }
__device__ __forceinline__ float tanh_f(float x) {
    float xc = fminf(fmaxf(x, -15.f), 15.f);
    float e = __expf(2.f * xc);
    return (e - 1.f) / (e + 1.f);
}

// WallT[n][k] fp16, n = g*256 + t (g: 0=i,1=o,2=u,3=f0,4=f1), k: [0,128)=x, [128,384)=h1, [384,640)=h2
__global__ void build_wallT(_Float16* __restrict__ WT,
    const float* __restrict__ Wioux, const float* __restrict__ Wfx,
    const float* __restrict__ Wiouh1, const float* __restrict__ Wfh11, const float* __restrict__ Wfh21,
    const float* __restrict__ Wiouh2, const float* __restrict__ Wfh12, const float* __restrict__ Wfh22)
{
    int e = blockIdx.x * 256 + threadIdx.x;   // < 1280*640 = 819200
    int nn = e / 640, k = e - nn * 640;
    int g = nn >> 8, t = nn & 255;
    float v;
    if (k < 128) {
        v = (g < 3) ? Wioux[k * 768 + nn] : Wfx[k * 256 + t];
    } else if (k < 384) {
        int kp = k - 128;
        v = (g < 3) ? Wiouh1[kp * 768 + nn] : ((g == 3) ? Wfh11[kp * 256 + t] : Wfh21[kp * 256 + t]);
    } else {
        int kp = k - 384;
        v = (g < 3) ? Wiouh2[kp * 768 + nn] : ((g == 3) ? Wfh12[kp * 256 + t] : Wfh22[kp * 256 + t]);
    }
    WT[e] = (_Float16)v;
}

__global__ void build_bias(float* __restrict__ bias,
    const float* __restrict__ bioux, const float* __restrict__ biouh1, const float* __restrict__ biouh2,
    const float* __restrict__ bfx, const float* __restrict__ bfh11, const float* __restrict__ bfh12,
    const float* __restrict__ bfh21, const float* __restrict__ bfh22)
{
    int e = blockIdx.x * 256 + threadIdx.x;
    if (e >= 1280) return;
    int g = e >> 8, t = e & 255;
    float v;
    if (g < 3)       v = bioux[e] + biouh1[e] + biouh2[e];
    else if (g == 3) v = bfx[t] + bfh11[t] + bfh12[t];
    else             v = bfx[t] + bfh21[t] + bfh22[t];
    bias[e] = v;
}

// emb -> fp16, with row 0 zeroed (reference does emb.at[0].set(0))
__global__ void build_embh(_Float16* __restrict__ EH, const float* __restrict__ emb) {
    int e = blockIdx.x * 256 + threadIdx.x;   // < 2048*128
    EH[e] = (e < DIN_) ? (_Float16)0.f : (_Float16)emb[e];
}

// One tree level as MFMA GEMM + fused LSTM epilogue.
// Block 256 thr = 4 waves (2x2): BM=64 rows x 64 features x G gates.
// A row r: [embh[ids[r]] (128) | h_prev[2r] (256) | h_prev[2r+1] (256)]  (fp16)
template<int G, int KTOT>
__global__ __launch_bounds__(256) void cell_mfma(
    const _Float16* __restrict__ WT, const float* __restrict__ bias,
    const int* __restrict__ ids, const _Float16* __restrict__ embh,
    const _Float16* __restrict__ h_prev, const float* __restrict__ c_prev,
    _Float16* __restrict__ h_out, float* __restrict__ c_out,
    int n, int ln, int off)
{
    constexpr int LDK = 40;                    // 32 + 8 pad halves: row stride 80B spreads banks
    __shared__ _Float16 As[64 * LDK];
    __shared__ _Float16 Bs[G * 64 * LDK];

    const int tid = threadIdx.x;
    const int lane = tid & 63;
    const int wid = tid >> 6;
    const int wy = wid >> 1, wx = wid & 1;
    const int l15 = lane & 15, lg = lane >> 4;
    const int rowBlock = blockIdx.x * 64;
    const int f0 = blockIdx.y * 64;

    f32x4 acc[2][2][G];                        // [row-tile][feat-tile][gate]
    #pragma unroll
    for (int rt = 0; rt < 2; ++rt)
        #pragma unroll
        for (int ft = 0; ft < 2; ++ft)
            #pragma unroll
            for (int g = 0; g < G; ++g) acc[rt][ft][g] = (f32x4)0.f;

    // A staging: thread owns (row ra, 8-half segment sa)
    const int ra = tid >> 2;
    const int sa = (tid & 3) * 8;
    const int r_g = rowBlock + ra;
    const int b = r_g >> ln;
    const int j = r_g & (n - 1);
    const _Float16* aEmb = embh + (size_t)ids[b * NODES_ + off + j] * DIN_ + sa;
    const _Float16* aH   = h_prev + (size_t)r_g * (2 * H_) + sa - DIN_;
    _Float16* aDst = &As[ra * LDK + sa];

    for (int k0 = 0; k0 < KTOT; k0 += 32) {
        // stage A (64 x 32 halves)
        *(half8*)aDst = (k0 < DIN_) ? *(const half8*)(aEmb + k0) : *(const half8*)(aH + k0);
        // stage B (G*64 x 32 halves) from WT[n][k]
        #pragma unroll
        for (int i = 0; i < G; ++i) {
            int c = tid + i * 256;
            int nb = c >> 2, sb = (c & 3) * 8;
            int g = nb >> 6, f = nb & 63;
            *(half8*)&Bs[nb * LDK + sb] =
                *(const half8*)(WT + (size_t)(g * 256 + f0 + f) * 640 + k0 + sb);
        }
        __syncthreads();
        half8 af0 = *(const half8*)&As[(wy * 32 + l15) * LDK + lg * 8];
        half8 af1 = *(const half8*)&As[(wy * 32 + 16 + l15) * LDK + lg * 8];
        #pragma unroll
        for (int ft = 0; ft < 2; ++ft)
            #pragma unroll
            for (int g = 0; g < G; ++g) {
                half8 bf = *(const half8*)&Bs[(g * 64 + wx * 32 + ft * 16 + l15) * LDK + lg * 8];
                acc[0][ft][g] = __builtin_amdgcn_mfma_f32_16x16x32_f16(af0, bf, acc[0][ft][g], 0, 0, 0);
                acc[1][ft][g] = __builtin_amdgcn_mfma_f32_16x16x32_f16(af1, bf, acc[1][ft][g], 0, 0, 0);
            }
        __syncthreads();
    }

    // fused epilogue: D row = (lane>>4)*4 + reg, col = lane&15 (per m89/m91 verified layout)
    #pragma unroll
    for (int rt = 0; rt < 2; ++rt) {
        int row0 = rowBlock + wy * 32 + rt * 16 + lg * 4;
        #pragma unroll
        for (int ft = 0; ft < 2; ++ft) {
            int tt = f0 + wx * 32 + ft * 16 + l15;
            float bi = bias[tt], bo = bias[H_ + tt], bu = bias[2 * H_ + tt];
            float bft0 = (G == 5) ? bias[3 * H_ + tt] : 0.f;
            float bft1 = (G == 5) ? bias[4 * H_ + tt] : 0.f;
            #pragma unroll
            for (int r = 0; r < 4; ++r) {
                int row = row0 + r;
                float vi = sigm(acc[rt][ft][0][r] + bi);
                float vo = sigm(acc[rt][ft][1][r] + bo);
                float vu = tanh_f(acc[rt][ft][2][r] + bu);
                float c;
                if constexpr (G == 5) {
                    float vf0 = sigm(acc[rt][ft][3][r] + bft0);
                    float vf1 = sigm(acc[rt][ft][4][r] + bft1);
                    const float* cpp = c_prev + (size_t)row * (2 * H_) + tt;
                    c = vi * vu + vf0 * cpp[0] + vf1 * cpp[H_];
                } else {
                    c = vi * vu;
                }
                size_t ob = (size_t)row * H_ + tt;
                h_out[ob] = (_Float16)(vo * tanh_f(c));
                c_out[ob] = c;
            }
        }
    }
}

// pred[b] = relu(h_root[b] @ Wl1 + bl1) @ Wl2 + bl2
__global__ void head_kernel(const _Float16* __restrict__ hroot,
    const float* __restrict__ Wl1, const float* __restrict__ bl1,
    const float* __restrict__ Wl2, const float* __restrict__ bl2,
    float* __restrict__ out)
{
    __shared__ float hrow[H_];
    __shared__ float red[256];
    int b = blockIdx.x; int tid = threadIdx.x;
    hrow[tid] = (float)hroot[(size_t)b * H_ + tid];
    __syncthreads();
    float v = 0.f;
    if (tid < 100) {
        float s = bl1[tid];
        for (int k = 0; k < H_; ++k) s = fmaf(hrow[k], Wl1[k * 100 + tid], s);
        v = fmaxf(s, 0.f) * Wl2[tid];
    }
    red[tid] = v;
    __syncthreads();
    for (int s = 128; s > 0; s >>= 1) { if (tid < s) red[tid] += red[tid + s]; __syncthreads(); }
    if (tid == 0) out[b] = red[0] + bl2[0];
}

extern "C" void kernel_launch(void* const* d_in, const int* in_sizes, int n_in,
                              void* d_out, int out_size, void* d_ws, size_t ws_size,
                              hipStream_t stream) {
    const int*   ids    = (const int*)d_in[0];
    const float* emb    = (const float*)d_in[1];
    const float* Wioux  = (const float*)d_in[2];
    const float* bioux  = (const float*)d_in[3];
    const float* Wiouh1 = (const float*)d_in[4];
    const float* biouh1 = (const float*)d_in[5];
    const float* Wiouh2 = (const float*)d_in[6];
    const float* biouh2 = (const float*)d_in[7];
    const float* Wfx    = (const float*)d_in[8];
    const float* bfx    = (const float*)d_in[9];
    const float* Wfh11  = (const float*)d_in[10];
    const float* bfh11  = (const float*)d_in[11];
    const float* Wfh12  = (const float*)d_in[12];
    const float* bfh12  = (const float*)d_in[13];
    const float* Wfh21  = (const float*)d_in[14];
    const float* bfh21  = (const float*)d_in[15];
    const float* Wfh22  = (const float*)d_in[16];
    const float* bfh22  = (const float*)d_in[17];
    const float* Wl1    = (const float*)d_in[18];
    const float* bl1    = (const float*)d_in[19];
    const float* Wl2    = (const float*)d_in[20];
    const float* bl2    = (const float*)d_in[21];
    float* out = (float*)d_out;

    // ws layout (bytes):
    // WT 1,638,400 | EH 524,288 | bias 5,120 | hA 33,554,432 | hB 16,777,216 | cA 67,108,864 | cB 33,554,432
    char* wsb = (char*)d_ws;
    _Float16* WT   = (_Float16*)(wsb);
    _Float16* EH   = (_Float16*)(wsb + 1638400);
    float*    bias = (float*)(wsb + 2162688);
    _Float16* hA   = (_Float16*)(wsb + 2167808);
    _Float16* hB   = (_Float16*)(wsb + 35722240);
    float*    cA   = (float*)(wsb + 52499456);
    float*    cB   = (float*)(wsb + 119608320);

    build_wallT<<<dim3(3200), 256, 0, stream>>>(WT, Wioux, Wfx, Wiouh1, Wfh11, Wfh21, Wiouh2, Wfh12, Wfh22);
    build_bias<<<dim3(5), 256, 0, stream>>>(bias, bioux, biouh1, biouh2, bfx, bfh11, bfh12, bfh21, bfh22);
    build_embh<<<dim3(1024), 256, 0, stream>>>(EH, emb);

    // level 0: K=128 (x only), gates iou
    cell_mfma<3, 128><<<dim3(1024, 4), 256, 0, stream>>>(WT, bias, ids, EH, hA, cA, hA, cA, 256, 8, 0);

    _Float16 *hp = hA, *hn = hB;
    float    *cp = cA, *cn = cB;
    int off = 256, n = 128, ln = 7;
    for (int lvl = 1; lvl < 9; ++lvl) {
        int M = B_ * n;
        cell_mfma<5, 640><<<dim3(M / 64, 4), 256, 0, stream>>>(WT, bias, ids, EH, hp, cp, hn, cn, n, ln, off);
        off += n; n >>= 1; ln -= 1;
        _Float16* t1 = hp; hp = hn; hn = t1;
        float*    t2 = cp; cp = cn; cn = t2;
    }

    head_kernel<<<dim3(256), 256, 0, stream>>>(hp, Wl1, bl1, Wl2, bl2, out);
}